// Round 4
// baseline (87.050 us; speedup 1.0000x reference)
//
#include <hip/hip_runtime.h>
#include <math.h>

#define NN    8192
#define KF    512
#define DF    64
#define NCH   32
#define EC    136   // E row stride: [pos h1 0..63][neg h1 64..127][onesP 128][onesN 129][pad 130..135]

// ============ K1: blocks 0..127: h1 = x@W^T (64 rows, 4x4 microtile), s1 = h1@w1
// ============     blocks 128..383: s2 = n@(W^T w2), 32 rows each
__global__ __launch_bounds__(256) void k_main(const float* __restrict__ x,
        const float* __restrict__ nmat, const float* __restrict__ W,
        const float* __restrict__ w1, const float* __restrict__ w2,
        float* __restrict__ h1, float* __restrict__ s1, float* __restrict__ s2) {
    const int tid = threadIdx.x;
    if (blockIdx.x < 128) {
        __shared__ float xs[32][68];   // [k][row], stride 68 floats = 272 B (16B mult)
        __shared__ float wt[32][64];   // [k][d]
        const int row0 = blockIdx.x * 64;
        const int ty = tid >> 4, tx = tid & 15;
        const int sr = tid >> 3;           // 0..31
        const int sc = (tid & 7) * 4;      // 0..28
        const int wd = tid & 63;
        const int wg = tid >> 6;           // 0..3
        float4 xv0 = *reinterpret_cast<const float4*>(x + (size_t)(row0 + sr) * KF + sc);
        float4 xv1 = *reinterpret_cast<const float4*>(x + (size_t)(row0 + 32 + sr) * KF + sc);
        float4 wv0 = *reinterpret_cast<const float4*>(W + (size_t)wd * KF + wg * 8);
        float4 wv1 = *reinterpret_cast<const float4*>(W + (size_t)wd * KF + wg * 8 + 4);
        float acc[4][4] = {};
        for (int kc = 0; kc < 16; ++kc) {
            __syncthreads();
            xs[sc+0][sr]=xv0.x; xs[sc+1][sr]=xv0.y; xs[sc+2][sr]=xv0.z; xs[sc+3][sr]=xv0.w;
            xs[sc+0][32+sr]=xv1.x; xs[sc+1][32+sr]=xv1.y; xs[sc+2][32+sr]=xv1.z; xs[sc+3][32+sr]=xv1.w;
            wt[wg*8+0][wd]=wv0.x; wt[wg*8+1][wd]=wv0.y; wt[wg*8+2][wd]=wv0.z; wt[wg*8+3][wd]=wv0.w;
            wt[wg*8+4][wd]=wv1.x; wt[wg*8+5][wd]=wv1.y; wt[wg*8+6][wd]=wv1.z; wt[wg*8+7][wd]=wv1.w;
            __syncthreads();
            if (kc < 15) {
                const int kk = (kc + 1) * 32;
                xv0 = *reinterpret_cast<const float4*>(x + (size_t)(row0 + sr) * KF + kk + sc);
                xv1 = *reinterpret_cast<const float4*>(x + (size_t)(row0 + 32 + sr) * KF + kk + sc);
                wv0 = *reinterpret_cast<const float4*>(W + (size_t)wd * KF + kk + wg * 8);
                wv1 = *reinterpret_cast<const float4*>(W + (size_t)wd * KF + kk + wg * 8 + 4);
            }
            #pragma unroll
            for (int k = 0; k < 32; ++k) {
                const float4 a4 = *reinterpret_cast<const float4*>(&xs[k][ty * 4]);
                const float4 b4 = *reinterpret_cast<const float4*>(&wt[k][tx * 4]);
                const float av[4] = {a4.x, a4.y, a4.z, a4.w};
                const float bv[4] = {b4.x, b4.y, b4.z, b4.w};
                #pragma unroll
                for (int i = 0; i < 4; ++i)
                    #pragma unroll
                    for (int j = 0; j < 4; ++j)
                        acc[i][j] = fmaf(av[i], bv[j], acc[i][j]);
            }
        }
        const float4 wv = *reinterpret_cast<const float4*>(w1 + tx * 4);
        #pragma unroll
        for (int i = 0; i < 4; ++i) {
            const int r = row0 + ty * 4 + i;
            *reinterpret_cast<float4*>(h1 + (size_t)r * DF + tx * 4) =
                make_float4(acc[i][0], acc[i][1], acc[i][2], acc[i][3]);
            float p = acc[i][0] * wv.x + acc[i][1] * wv.y + acc[i][2] * wv.z + acc[i][3] * wv.w;
            #pragma unroll
            for (int off = 1; off < 16; off <<= 1) p += __shfl_xor(p, off);
            if (tx == 0) s1[r] = p;
        }
    } else {
        __shared__ float v2s[KF];
        const int row0 = (blockIdx.x - 128) * 32;
        float a0 = 0.f, a1 = 0.f;
        for (int d = 0; d < DF; ++d) {
            const float wd2 = w2[d];
            a0 = fmaf(W[(size_t)d * KF + tid],       wd2, a0);
            a1 = fmaf(W[(size_t)d * KF + 256 + tid], wd2, a1);
        }
        v2s[tid] = a0; v2s[tid + 256] = a1;
        __syncthreads();
        const int lane = tid & 63, w = tid >> 6;
        const float4 b0 = *reinterpret_cast<const float4*>(&v2s[lane * 4]);
        const float4 b1 = *reinterpret_cast<const float4*>(&v2s[256 + lane * 4]);
        for (int rr = 0; rr < 8; ++rr) {
            const int row = row0 + w * 8 + rr;
            const float4 n0 = *reinterpret_cast<const float4*>(nmat + (size_t)row * KF + lane * 4);
            const float4 n1 = *reinterpret_cast<const float4*>(nmat + (size_t)row * KF + 256 + lane * 4);
            float acc = n0.x * b0.x;
            acc = fmaf(n0.y, b0.y, acc); acc = fmaf(n0.z, b0.z, acc); acc = fmaf(n0.w, b0.w, acc);
            acc = fmaf(n1.x, b1.x, acc); acc = fmaf(n1.y, b1.y, acc);
            acc = fmaf(n1.z, b1.z, acc); acc = fmaf(n1.w, b1.w, acc);
            #pragma unroll
            for (int off = 32; off; off >>= 1) acc += __shfl_xor(acc, off);
            if (lane == 0) s2[row] = acc;
        }
    }
}

__device__ __forceinline__ unsigned int f2key(float f) {
    unsigned int u = __float_as_uint(f);
    return u ^ ((u >> 31) ? 0xFFFFFFFFu : 0x80000000u);   // monotone total order
}

// ============ K2: rank all j by (s2[j], j) via sortable keys; scatter sorted arrays + exp weights
__global__ __launch_bounds__(256) void k_rank(const float* __restrict__ s2,
        int* __restrict__ order, float* __restrict__ s2s,
        double* __restrict__ wpos, double* __restrict__ wneg) {
    __shared__ unsigned int sk[NN];   // 32 KB of sortable keys
    __shared__ int part[256];
    const int tid = threadIdx.x;
    {
        const float4* src = reinterpret_cast<const float4*>(s2);
        #pragma unroll
        for (int t = 0; t < 8; ++t) {
            const float4 v = src[tid + t * 256];
            const int b = (tid + t * 256) * 4;
            sk[b] = f2key(v.x); sk[b+1] = f2key(v.y); sk[b+2] = f2key(v.z); sk[b+3] = f2key(v.w);
        }
    }
    __syncthreads();
    const int jl = tid & 15, seg = tid >> 4;
    const int j = blockIdx.x * 16 + jl;
    const unsigned int mk = sk[j];
    const int base = seg * 512;
    int cnt = 0;
    for (int q = 0; q < 128; ++q) {
        const int e = (q * 4 + seg * 4) & 511;
        const int idx = base + e;
        const uint4 v = *reinterpret_cast<const uint4*>(&sk[idx]);
        cnt += (v.x < mk) | ((v.x == mk) & (idx     < j));
        cnt += (v.y < mk) | ((v.y == mk) & (idx + 1 < j));
        cnt += (v.z < mk) | ((v.z == mk) & (idx + 2 < j));
        cnt += (v.w < mk) | ((v.w == mk) & (idx + 3 < j));
    }
    part[tid] = cnt;
    __syncthreads();
    if (tid < 16) {
        int r = 0;
        #pragma unroll
        for (int s = 0; s < 16; ++s) r += part[s * 16 + tid];
        const int jj = blockIdx.x * 16 + tid;
        const float v = s2[jj];
        order[r] = jj;
        s2s[r] = v;
        wpos[r] = exp((double)v);
        wneg[r] = exp(0.2 * (double)v);
    }
}

// col-group helpers: 17 groups; g<8 -> pos h1 cols 8g.. ; g<16 -> neg h1; g==16 -> ones cols {128,129}
__device__ __forceinline__ void load_vals(int g, int p, const float* __restrict__ h1,
        const int* __restrict__ order, const double* __restrict__ wpos,
        const double* __restrict__ wneg, double* vals, int& ncols, int& colbase) {
    if (g < 16) {
        ncols = 8;
        const int d0 = (g < 8) ? 8 * g : 8 * (g - 8);
        colbase = (g < 8) ? d0 : 64 + d0;
        const double wgt = (g < 8) ? wpos[p] : wneg[p];
        const float* hp = h1 + (size_t)order[p] * DF + d0;
        const float4 h0 = *reinterpret_cast<const float4*>(hp);
        const float4 h4 = *reinterpret_cast<const float4*>(hp + 4);
        vals[0]=wgt*h0.x; vals[1]=wgt*h0.y; vals[2]=wgt*h0.z; vals[3]=wgt*h0.w;
        vals[4]=wgt*h4.x; vals[5]=wgt*h4.y; vals[6]=wgt*h4.z; vals[7]=wgt*h4.w;
    } else {
        ncols = 2; colbase = 128;
        vals[0] = wpos[p]; vals[1] = wneg[p];
    }
}

// ============ K3: per-(col,chunk) totals cT[col][c]
__global__ __launch_bounds__(256) void k_csum(const float* __restrict__ h1,
        const int* __restrict__ order, const double* __restrict__ wpos,
        const double* __restrict__ wneg, double* __restrict__ cT) {
    const int g = blockIdx.x, c = blockIdx.y;
    const int tid = threadIdx.x, lane = tid & 63, w = tid >> 6;
    const int p = c * 256 + tid;
    double vals[8]; int ncols, colbase;
    load_vals(g, p, h1, order, wpos, wneg, vals, ncols, colbase);
    __shared__ double red[4][8];
    for (int jj = 0; jj < ncols; ++jj) {
        double r = vals[jj];
        #pragma unroll
        for (int off = 32; off; off >>= 1) r += __shfl_xor(r, off);
        if (lane == 0) red[w][jj] = r;
    }
    __syncthreads();
    if (tid < ncols)
        cT[(size_t)(colbase + tid) * NCH + c] = red[0][tid] + red[1][tid] + red[2][tid] + red[3][tid];
}

// ============ K4: exclusive scan -> E rows (8-col contiguous 64B stores); c==31 writes totals row
__global__ __launch_bounds__(256) void k_scan(const float* __restrict__ h1,
        const int* __restrict__ order, const double* __restrict__ wpos,
        const double* __restrict__ wneg, const double* __restrict__ cT,
        double* __restrict__ E) {
    const int g = blockIdx.x, c = blockIdx.y;
    const int tid = threadIdx.x, lane = tid & 63, w = tid >> 6;
    const int p = c * 256 + tid;
    double vals[8], inc8[8]; int ncols, colbase;
    load_vals(g, p, h1, order, wpos, wneg, vals, ncols, colbase);
    __shared__ double cOs[8];
    __shared__ double wtot[4][8];
    if (tid < ncols) {
        double s = 0.0;
        const double* ct = cT + (size_t)(colbase + tid) * NCH;
        for (int cc = 0; cc < c; ++cc) s += ct[cc];
        cOs[tid] = s;
    }
    for (int jj = 0; jj < ncols; ++jj) {
        double incl = vals[jj];
        #pragma unroll
        for (int off = 1; off < 64; off <<= 1) {
            double t = __shfl_up(incl, off);
            if (lane >= off) incl += t;
        }
        inc8[jj] = incl;
        if (lane == 63) wtot[w][jj] = incl;
    }
    __syncthreads();
    double* Ep = E + (size_t)p * EC + colbase;
    for (int jj = 0; jj < ncols; ++jj) {
        double woff = cOs[jj];
        for (int ww = 0; ww < w; ++ww) woff += wtot[ww][jj];
        Ep[jj] = woff + inc8[jj] - vals[jj];
    }
    if (c == NCH - 1 && tid < ncols)
        E[(size_t)NN * EC + colbase + tid] =
            cOs[tid] + wtot[0][tid] + wtot[1][tid] + wtot[2][tid] + wtot[3][tid];
}

// ============ K5: per-row binary search + combine
__global__ __launch_bounds__(256) void k_out(const float* __restrict__ s1,
        const float* __restrict__ s2s, const double* __restrict__ E,
        float* __restrict__ out) {
    const int lane = threadIdx.x & 63, wave = threadIdx.x >> 6;
    const int i = blockIdx.x * 4 + wave;
    const float s1v = s1[i];
    const float t = -s1v;
    int lo = 0, hi = NN;
    while (lo < hi) {
        int mid = (lo + hi) >> 1;
        if (s2s[mid] < t) lo = mid + 1; else hi = mid;
    }
    const double* Ek = E + (size_t)lo * EC;
    const double* Et = E + (size_t)NN * EC;
    const double e1 = exp((double)s1v);
    const double e2 = exp(0.2 * (double)s1v);
    const double num = e1 * (Et[lane] - Ek[lane]) + e2 * Ek[64 + lane];
    const double den = e1 * (Et[128] - Ek[128]) + e2 * Ek[129];
    out[(size_t)i * DF + lane] = (float)(num / den);
}

extern "C" void kernel_launch(void* const* d_in, const int* in_sizes, int n_in,
                              void* d_out, int out_size, void* d_ws, size_t ws_size,
                              hipStream_t stream) {
    const float* x    = (const float*)d_in[0];
    const float* nmat = (const float*)d_in[1];
    const float* W    = (const float*)d_in[2];
    const float* w1   = (const float*)d_in[3];
    const float* w2   = (const float*)d_in[4];
    float* out = (float*)d_out;

    char* ws = (char*)d_ws;
    size_t off = 0;
    auto alloc = [&](size_t bytes) -> void* {
        void* p = ws + off;
        off += (bytes + 255) & ~(size_t)255;
        return p;
    };
    float*  h1    = (float*)alloc((size_t)NN * DF * 4);        // 2 MB
    float*  s1    = (float*)alloc((size_t)NN * 4);
    float*  s2    = (float*)alloc((size_t)NN * 4);
    int*    order = (int*)alloc((size_t)NN * 4);
    float*  s2s   = (float*)alloc((size_t)NN * 4);
    double* wpos  = (double*)alloc((size_t)NN * 8);
    double* wneg  = (double*)alloc((size_t)NN * 8);
    double* cT    = (double*)alloc((size_t)130 * NCH * 8);
    double* E     = (double*)alloc((size_t)(NN + 1) * EC * 8); // 8.9 MB

    k_main<<<384, 256, 0, stream>>>(x, nmat, W, w1, w2, h1, s1, s2);
    k_rank<<<512, 256, 0, stream>>>(s2, order, s2s, wpos, wneg);
    k_csum<<<dim3(17, NCH), 256, 0, stream>>>(h1, order, wpos, wneg, cT);
    k_scan<<<dim3(17, NCH), 256, 0, stream>>>(h1, order, wpos, wneg, cT, E);
    k_out<<<NN / 4, 256, 0, stream>>>(s1, s2s, E, out);
}